// Round 4
// baseline (2535.320 us; speedup 1.0000x reference)
//
#include <hip/hip_runtime.h>
#include <stdint.h>

#define SEQ 8192
#define B   40
#define EMBD 64
#define HID 40
#define VOCAB 201
#define LOG2E 1.4426950408889634f

typedef float v2f __attribute__((ext_vector_type(2)));

__device__ __forceinline__ float fexp2(float x) { float r; asm("v_exp_f32 %0, %1" : "=v"(r) : "v"(x)); return r; }
__device__ __forceinline__ float frcp (float x) { float r; asm("v_rcp_f32 %0, %1" : "=v"(r) : "v"(x)); return r; }
__device__ __forceinline__ float sigm (float x) { return frcp(1.f + fexp2(-LOG2E * x)); }
__device__ __forceinline__ float tanh_(float x) { return fmaf(2.f, frcp(1.f + fexp2(-2.f * LOG2E * x)), -1.f); }
__device__ __forceinline__ float rdlane(float v, int k) {
    int r = __builtin_amdgcn_readlane(__builtin_bit_cast(int, v), k);
    return __builtin_bit_cast(float, r);
}

// ---------------- kernel A: table4[v][e] = (i,f,g,o) gate x-parts+bias ----------------
__global__ void setup_kernel(const float* __restrict__ emb, const float* __restrict__ Wih,
                             const float* __restrict__ bih, const float* __restrict__ bhh,
                             float4* __restrict__ table4) {
    const int v = blockIdx.x;          // 0..200
    const int e = threadIdx.x;         // 0..63, active < 40
    if (e >= HID) return;
    const float* er = emb + v * EMBD;
    float acc[4];
#pragma unroll
    for (int g = 0; g < 4; ++g) {
        const int j = g * HID + e;
        const float* wr = Wih + j * EMBD;
        float a = bih[j] + bhh[j];
#pragma unroll 8
        for (int k = 0; k < EMBD; ++k) a = fmaf(er[k], wr[k], a);
        acc[g] = a;
    }
    table4[v * HID + e] = make_float4(acc[0], acc[1], acc[2], acc[3]);
}

// ---------------- kernel B: encoder, 1 chain per block, ONE wave, full VGPR budget ----------------
__global__ __attribute__((amdgpu_flat_work_group_size(64, 64), amdgpu_waves_per_eu(1, 1)))
void enc_kernel(const int* __restrict__ src,
                const float* __restrict__ Whh,
                const float4* __restrict__ tbl,
                float* __restrict__ est) {
    const int b    = blockIdx.x;
    const int lane = threadIdx.x;
    const int e    = (lane < HID) ? lane : 0;   // clamp idle lanes to element 0

    __shared__ int ssrc[SEQ];
    for (int t = lane; t < SEQ; t += 64) ssrc[t] = src[t * B + b];

    // weights packed per lane: wif[k]=(Wi[e][k],Wf[e][k]), wgo[k]=(Wg[e][k],Wo[e][k])
    v2f wif[40], wgo[40];
#pragma unroll
    for (int r = 0; r < 10; ++r) {
        float4 ai = *reinterpret_cast<const float4*>(&Whh[(0 * HID + e) * HID + 4 * r]);
        float4 af = *reinterpret_cast<const float4*>(&Whh[(1 * HID + e) * HID + 4 * r]);
        float4 ag = *reinterpret_cast<const float4*>(&Whh[(2 * HID + e) * HID + 4 * r]);
        float4 ao = *reinterpret_cast<const float4*>(&Whh[(3 * HID + e) * HID + 4 * r]);
        wif[4*r+0] = (v2f){ai.x, af.x}; wif[4*r+1] = (v2f){ai.y, af.y};
        wif[4*r+2] = (v2f){ai.z, af.z}; wif[4*r+3] = (v2f){ai.w, af.w};
        wgo[4*r+0] = (v2f){ag.x, ao.x}; wgo[4*r+1] = (v2f){ag.y, ao.y};
        wgo[4*r+2] = (v2f){ag.z, ao.z}; wgo[4*r+3] = (v2f){ag.w, ao.w};
    }

    float c = 0.f, h = 0.f;
    __syncthreads();   // ssrc staged (single wave, cheap)

    int i3 = ssrc[3];
    float4 tq0 = tbl[ssrc[0] * HID + e];
    float4 tq1 = tbl[ssrc[1] * HID + e];
    float4 tq2 = tbl[ssrc[2] * HID + e];

#pragma unroll 4
    for (int t = 0; t < SEQ; ++t) {
        // prefetch x-part for t+3, index for t+4
        float4 tq3 = tbl[i3 * HID + e];
        i3 = ssrc[(t + 4) & (SEQ - 1)];

        v2f aif0 = (v2f){tq0.x, tq0.y}, aif1 = (v2f){0.f,0.f}, aif2 = (v2f){0.f,0.f}, aif3 = (v2f){0.f,0.f};
        v2f ago0 = (v2f){tq0.z, tq0.w}, ago1 = (v2f){0.f,0.f}, ago2 = (v2f){0.f,0.f}, ago3 = (v2f){0.f,0.f};
#pragma unroll
        for (int k = 0; k < 40; k += 4) {
            float h0 = rdlane(h, k + 0);
            float h1 = rdlane(h, k + 1);
            float h2 = rdlane(h, k + 2);
            float h3 = rdlane(h, k + 3);
            aif0 = __builtin_elementwise_fma(wif[k+0], (v2f){h0, h0}, aif0);
            ago0 = __builtin_elementwise_fma(wgo[k+0], (v2f){h0, h0}, ago0);
            aif1 = __builtin_elementwise_fma(wif[k+1], (v2f){h1, h1}, aif1);
            ago1 = __builtin_elementwise_fma(wgo[k+1], (v2f){h1, h1}, ago1);
            aif2 = __builtin_elementwise_fma(wif[k+2], (v2f){h2, h2}, aif2);
            ago2 = __builtin_elementwise_fma(wgo[k+2], (v2f){h2, h2}, ago2);
            aif3 = __builtin_elementwise_fma(wif[k+3], (v2f){h3, h3}, aif3);
            ago3 = __builtin_elementwise_fma(wgo[k+3], (v2f){h3, h3}, ago3);
        }
        v2f AIF = (aif0 + aif1) + (aif2 + aif3);
        v2f AGO = (ago0 + ago1) + (ago2 + ago3);

        float si = sigm(AIF.x), sf = sigm(AIF.y);
        float tg = tanh_(AGO.x), so = sigm(AGO.y);
        c = fmaf(sf, c, si * tg);
        h = so * tanh_(c);

        tq0 = tq1; tq1 = tq2; tq2 = tq3;
    }

    if (lane < HID) {
        est[b * 80 + lane]       = h;
        est[b * 80 + HID + lane] = c;
    }
}

// ---------------- kernel C: decoder, 40 steps, 1 chain per block (3 waves, proven) ----------------
__global__ __launch_bounds__(192, 1) void dec_kernel(const float* __restrict__ dinp,
                                                     const float* __restrict__ Wih,
                                                     const float* __restrict__ Whh,
                                                     const float* __restrict__ bih,
                                                     const float* __restrict__ bhh,
                                                     const float* __restrict__ est,
                                                     float* __restrict__ out) {
    const int b    = blockIdx.x;
    const int tid  = threadIdx.x;
    const int lane = tid & 63;
    const int w    = tid >> 6;
    const int tt   = lane >> 4;
    const int q    = lane & 15;
    const int e    = 16 * w + q;
    const bool valid = (e < HID);
    const bool own   = valid && (tt == 0);
    const int j    = tt * HID + (valid ? e : 0);

    __shared__ __align__(16) float hbuf[2][48];

    float4 wi4[10], wh4[10];
#pragma unroll
    for (int r = 0; r < 10; ++r) {
        float4 ti = *reinterpret_cast<const float4*>(&Wih[j * HID + 4 * r]);
        float4 th = *reinterpret_cast<const float4*>(&Whh[j * HID + 4 * r]);
        if (!valid) { ti = make_float4(0,0,0,0); th = make_float4(0,0,0,0); }
        wi4[r] = ti; wh4[r] = th;
    }
    const float bj = valid ? (bih[j] + bhh[j]) : 0.f;

    const float mcoef = (tt == 2) ? (-2.f * LOG2E) : (-LOG2E);
    const float vsc   = (tt == 2) ? 2.f : 1.f;
    const float voff  = (tt == 2) ? -1.f : 0.f;

    float4 xr4[10], hr4[10];
#pragma unroll
    for (int r = 0; r < 10; ++r) {
        xr4[r] = *reinterpret_cast<const float4*>(&dinp[b * HID + 4 * r]);
        hr4[r] = *reinterpret_cast<const float4*>(&est[b * 80 + 4 * r]);
    }
    float c = valid ? est[b * 80 + HID + e] : 0.f;

    for (int t = 0; t < B; ++t) {
        float a0 = bj, a1 = 0.f, a2 = 0.f, a3 = 0.f;
#pragma unroll
        for (int r = 0; r < 10; ++r) {
            a0 = fmaf(wi4[r].x, xr4[r].x, a0);
            a1 = fmaf(wi4[r].y, xr4[r].y, a1);
            a2 = fmaf(wi4[r].z, xr4[r].z, a2);
            a3 = fmaf(wi4[r].w, xr4[r].w, a3);
            a0 = fmaf(wh4[r].x, hr4[r].x, a0);
            a1 = fmaf(wh4[r].y, hr4[r].y, a1);
            a2 = fmaf(wh4[r].z, hr4[r].z, a2);
            a3 = fmaf(wh4[r].w, hr4[r].w, a3);
        }
        float xg = (a0 + a1) + (a2 + a3);

        float E   = fexp2(mcoef * xg);
        float v   = frcp(1.f + E);
        float act = fmaf(vsc, v, voff);

        float ig = __shfl(act, q);
        float fg = __shfl(act, q + 16);
        float gg = __shfl(act, q + 32);
        float og = __shfl(act, q + 48);

        c = fmaf(fg, c, ig * gg);
        float Ec = fexp2(-2.f * LOG2E * c);
        float th = fmaf(2.f, frcp(1.f + Ec), -1.f);
        float h  = og * th;

        if (own) out[(t * B + b) * HID + e] = h;

        if (own) hbuf[t & 1][e] = h;
        __syncthreads();
#pragma unroll
        for (int r = 0; r < 10; ++r) {
            hr4[r] = *reinterpret_cast<const float4*>(&hbuf[t & 1][4 * r]);
            xr4[r] = hr4[r];   // next input is current output
        }
    }
}

extern "C" void kernel_launch(void* const* d_in, const int* in_sizes, int n_in,
                              void* d_out, int out_size, void* d_ws, size_t ws_size,
                              hipStream_t stream) {
    const int*   src  = (const int*)  d_in[0];
    const float* dinp = (const float*)d_in[1];
    const float* emb  = (const float*)d_in[2];
    const float* eWih = (const float*)d_in[3];
    const float* eWhh = (const float*)d_in[4];
    const float* ebih = (const float*)d_in[5];
    const float* ebhh = (const float*)d_in[6];
    const float* dWih = (const float*)d_in[7];
    const float* dWhh = (const float*)d_in[8];
    const float* dbih = (const float*)d_in[9];
    const float* dbhh = (const float*)d_in[10];
    float* out = (float*)d_out;

    float4* table4 = (float4*)d_ws;                       // 201*40 float4
    float*  est    = (float*)(table4 + VOCAB * HID);      // 40*80 floats

    hipLaunchKernelGGL(setup_kernel, dim3(VOCAB), dim3(64), 0, stream, emb, eWih, ebih, ebhh, table4);
    hipLaunchKernelGGL(enc_kernel,   dim3(B),     dim3(64), 0, stream, src, eWhh, table4, est);
    hipLaunchKernelGGL(dec_kernel,   dim3(B),     dim3(192), 0, stream, dinp, dWih, dWhh, dbih, dbhh, est, out);
}